// Round 1
// baseline (97.051 us; speedup 1.0000x reference)
//
#include <hip/hip_runtime.h>
#include <hip/hip_bf16.h>

// Problem constants
#define NB   65536   // batch rows
#define ND   1024    // feature dim (K)
#define NT   64      // trees (N)

typedef __attribute__((ext_vector_type(8))) short bf16x8;
typedef __attribute__((ext_vector_type(4))) float f32x4;

__device__ __forceinline__ short f2bf_s(float f) {
    __hip_bfloat16 h = __float2bfloat16(f);
    return __builtin_bit_cast(short, h);
}

// ---- prep: convert feature_selectors [64][1024] f32 -> bf16 in d_ws ----
__global__ __launch_bounds__(256) void prep_kernel(const float* __restrict__ F,
                                                   __hip_bfloat16* __restrict__ Fb) {
    int idx = blockIdx.x * 256 + threadIdx.x;  // grid = 256 blocks -> 65536 exactly
    Fb[idx] = __float2bfloat16(F[idx]);
}

// ---- main: block = 256 threads (4 waves), each wave does 16 rows x 64 trees ----
template <bool PREPPED>
__global__ __launch_bounds__(256) void node_main(const float* __restrict__ x,
                                                 const void* __restrict__ Fv,
                                                 const float* __restrict__ thr,
                                                 const float* __restrict__ lw,
                                                 float* __restrict__ out) {
    __shared__ float lds_lw[256];   // leaf_weights [64][2][2]
    __shared__ float lds_thr[64];   // thresholds [64]

    const int tid = threadIdx.x;
    lds_lw[tid] = lw[tid];
    if (tid < 64) lds_thr[tid] = thr[tid];
    __syncthreads();

    const int wave = tid >> 6;
    const int lane = tid & 63;
    const int c = lane & 15;        // A-row / B-col / C-col within 16
    const int g = lane >> 4;        // k-group (0..3)

    const long rowbase = (long)blockIdx.x * 64 + (long)wave * 16;
    const float* xp = x + (rowbase + c) * ND + g * 8;   // A fragment base

    f32x4 acc[4];
#pragma unroll
    for (int nt = 0; nt < 4; ++nt) acc[nt] = (f32x4){0.f, 0.f, 0.f, 0.f};

    const __hip_bfloat16* Fb = (const __hip_bfloat16*)Fv;
    const float*          Ff = (const float*)Fv;

#pragma unroll 4
    for (int kk = 0; kk < 32; ++kk) {
        const int kb = kk * 32;
        // ---- A fragment: 8 f32 -> 8 bf16 ----
        float4 a0 = *(const float4*)(xp + kb);
        float4 a1 = *(const float4*)(xp + kb + 4);
        bf16x8 af;
        af[0] = f2bf_s(a0.x); af[1] = f2bf_s(a0.y);
        af[2] = f2bf_s(a0.z); af[3] = f2bf_s(a0.w);
        af[4] = f2bf_s(a1.x); af[5] = f2bf_s(a1.y);
        af[6] = f2bf_s(a1.z); af[7] = f2bf_s(a1.w);

        // ---- B fragments: 4 n-tiles of 16 trees ----
#pragma unroll
        for (int nt = 0; nt < 4; ++nt) {
            const int n = nt * 16 + c;
            bf16x8 bfrag;
            if constexpr (PREPPED) {
                bfrag = *(const bf16x8*)(Fb + (long)n * ND + g * 8 + kb);
            } else {
                const float* fp = Ff + (long)n * ND + g * 8 + kb;
                float4 b0 = *(const float4*)(fp);
                float4 b1 = *(const float4*)(fp + 4);
                bfrag[0] = f2bf_s(b0.x); bfrag[1] = f2bf_s(b0.y);
                bfrag[2] = f2bf_s(b0.z); bfrag[3] = f2bf_s(b0.w);
                bfrag[4] = f2bf_s(b1.x); bfrag[5] = f2bf_s(b1.y);
                bfrag[6] = f2bf_s(b1.z); bfrag[7] = f2bf_s(b1.w);
            }
            acc[nt] = __builtin_amdgcn_mfma_f32_16x16x32_bf16(af, bfrag, acc[nt], 0, 0, 0);
        }
    }

    // ---- epilogue: sigmoid + leaf combine + 16-lane reduce ----
    // C/D layout: col (tree) = nt*16 + c, row (batch) = g*4 + reg
#pragma unroll
    for (int reg = 0; reg < 4; ++reg) {
        float o0 = 0.f, o1 = 0.f;
#pragma unroll
        for (int nt = 0; nt < 4; ++nt) {
            const int t = nt * 16 + c;
            const float logit = acc[nt][reg] - lds_thr[t];
            const float p = 1.0f / (1.0f + __expf(-logit));
            const float w00 = lds_lw[t * 4 + 0];
            const float w01 = lds_lw[t * 4 + 1];
            const float w10 = lds_lw[t * 4 + 2];
            const float w11 = lds_lw[t * 4 + 3];
            o0 += w10 + p * (w00 - w10);
            o1 += w11 + p * (w01 - w11);
        }
#pragma unroll
        for (int m = 8; m >= 1; m >>= 1) {
            o0 += __shfl_xor(o0, m, 64);
            o1 += __shfl_xor(o1, m, 64);
        }
        if (c == 0) {
            const long row = rowbase + g * 4 + reg;
            *(float2*)(out + row * 2) = make_float2(o0, o1);
        }
    }
}

extern "C" void kernel_launch(void* const* d_in, const int* in_sizes, int n_in,
                              void* d_out, int out_size, void* d_ws, size_t ws_size,
                              hipStream_t stream) {
    const float* x   = (const float*)d_in[0];
    const float* fs  = (const float*)d_in[1];
    const float* thr = (const float*)d_in[2];
    const float* lw  = (const float*)d_in[3];
    float* out = (float*)d_out;

    const size_t FB_BYTES = (size_t)NT * ND * sizeof(__hip_bfloat16);  // 128 KB
    if (ws_size >= FB_BYTES) {
        __hip_bfloat16* Fb = (__hip_bfloat16*)d_ws;
        prep_kernel<<<256, 256, 0, stream>>>(fs, Fb);
        node_main<true><<<NB / 64, 256, 0, stream>>>(x, (const void*)Fb, thr, lw, out);
    } else {
        node_main<false><<<NB / 64, 256, 0, stream>>>(x, (const void*)fs, thr, lw, out);
    }
}

// Round 2
// 64.155 us; speedup vs baseline: 1.5128x; 1.5128x over previous
//
#include <hip/hip_runtime.h>
#include <hip/hip_bf16.h>

// Problem constants
#define NB   65536   // batch rows
#define ND   1024    // feature dim (K)
#define NT   64      // trees (N)
#define BK   128     // K-chunk in floats
#define NCH  (ND / BK)   // 8 chunks
#define ROWS 64      // rows per block

typedef __attribute__((ext_vector_type(8))) short bf16x8;
typedef __attribute__((ext_vector_type(4))) float f32x4;

__device__ __forceinline__ short f2bf_s(float f) {
    __hip_bfloat16 h = __float2bfloat16(f);
    return __builtin_bit_cast(short, h);
}

// ---- prep: convert feature_selectors [64][1024] f32 -> bf16 in d_ws ----
__global__ __launch_bounds__(256) void prep_kernel(const float* __restrict__ F,
                                                   __hip_bfloat16* __restrict__ Fb) {
    int idx = blockIdx.x * 256 + threadIdx.x;  // grid = 256 -> 65536 elements
    Fb[idx] = __float2bfloat16(F[idx]);
}

// ---- main: 256 threads / 4 waves; block owns 64 rows; wave w owns trees [16w,16w+16) ----
template <bool PREPPED>
__global__ __launch_bounds__(256, 4) void node_main(const float* __restrict__ x,
                                                    const void* __restrict__ Fv,
                                                    const float* __restrict__ thr,
                                                    const float* __restrict__ lw,
                                                    float* __restrict__ out) {
    __shared__ __hip_bfloat16 Abuf[2][ROWS * BK];   // 2 x 16 KB, XOR-swizzled bf16
    __shared__ float partials[4][ROWS][2];          // per-wave output partials

    const int tid  = threadIdx.x;
    const int w    = tid >> 6;      // wave id -> n-tile
    const int lane = tid & 63;
    const int c    = lane & 15;     // MFMA row/col-within-16
    const int g    = lane >> 4;     // k-group
    const long blockRow = (long)blockIdx.x * ROWS;

    // staging mapping: 4 threads per row, each 32 consecutive floats
    const int srow = tid >> 2;      // 0..63
    const int sj   = tid & 3;       // 0..3
    const float* xrow = x + (blockRow + srow) * ND + sj * 32;

    // per-lane tree constants (tree fixed per lane!)
    const int   t     = w * 16 + c;
    const float thr_t = thr[t];
    const float w00 = lw[t * 4 + 0], w01 = lw[t * 4 + 1];
    const float w10 = lw[t * 4 + 2], w11 = lw[t * 4 + 3];

    const __hip_bfloat16* Fb = (const __hip_bfloat16*)Fv;
    const float*          Ff = (const float*)Fv;

    f32x4 acc[4];
#pragma unroll
    for (int rt = 0; rt < 4; ++rt) acc[rt] = (f32x4){0.f, 0.f, 0.f, 0.f};

    float4 rA[8];

    auto load_chunk = [&](int ch) {
#pragma unroll
        for (int i = 0; i < 8; ++i)
            rA[i] = *(const float4*)(xrow + ch * BK + i * 4);
    };
    auto stage_write = [&](int buf) {
#pragma unroll
        for (int i = 0; i < 4; ++i) {
            float4 a = rA[2 * i], b = rA[2 * i + 1];
            bf16x8 v;
            v[0] = f2bf_s(a.x); v[1] = f2bf_s(a.y); v[2] = f2bf_s(a.z); v[3] = f2bf_s(a.w);
            v[4] = f2bf_s(b.x); v[5] = f2bf_s(b.y); v[6] = f2bf_s(b.z); v[7] = f2bf_s(b.w);
            const int slot = (sj * 4 + i) ^ (srow & 7);   // T2 XOR swizzle, 16B granules
            *(bf16x8*)(&Abuf[buf][srow * BK + slot * 8]) = v;
        }
    };

    // prologue: fill buf0, issue chunk-1 loads
    load_chunk(0);
    stage_write(0);
    load_chunk(1);
    __syncthreads();

    for (int ch = 0; ch < NCH; ++ch) {
        const int cur = ch & 1;
        // ---- compute chunk ch ----
#pragma unroll
        for (int kk = 0; kk < 4; ++kk) {
            bf16x8 bfrag;
            const long boff = (long)t * ND + (long)ch * BK + kk * 32 + g * 8;
            if constexpr (PREPPED) {
                bfrag = *(const bf16x8*)(Fb + boff);
            } else {
                float4 b0 = *(const float4*)(Ff + boff);
                float4 b1 = *(const float4*)(Ff + boff + 4);
                bfrag[0] = f2bf_s(b0.x); bfrag[1] = f2bf_s(b0.y);
                bfrag[2] = f2bf_s(b0.z); bfrag[3] = f2bf_s(b0.w);
                bfrag[4] = f2bf_s(b1.x); bfrag[5] = f2bf_s(b1.y);
                bfrag[6] = f2bf_s(b1.z); bfrag[7] = f2bf_s(b1.w);
            }
#pragma unroll
            for (int rt = 0; rt < 4; ++rt) {
                const int r    = rt * 16 + c;
                const int slot = (kk * 4 + g) ^ (r & 7);
                bf16x8 afrag = *(const bf16x8*)(&Abuf[cur][r * BK + slot * 8]);
                acc[rt] = __builtin_amdgcn_mfma_f32_16x16x32_bf16(afrag, bfrag, acc[rt], 0, 0, 0);
            }
        }
        // ---- stage chunk ch+1 (rA already in flight), issue chunk ch+2 ----
        if (ch < NCH - 1) {
            stage_write(cur ^ 1);
            if (ch < NCH - 2) load_chunk(ch + 2);
        }
        __syncthreads();
    }

    // ---- epilogue: sigmoid + leaf combine + tree reduction ----
#pragma unroll
    for (int rt = 0; rt < 4; ++rt) {
#pragma unroll
        for (int reg = 0; reg < 4; ++reg) {
            const float logit = acc[rt][reg] - thr_t;
            const float p = 1.0f / (1.0f + __expf(-logit));
            float o0 = w10 + p * (w00 - w10);
            float o1 = w11 + p * (w01 - w11);
            // butterfly over the 16 trees (c bits of lane)
#pragma unroll
            for (int m = 1; m < 16; m <<= 1) {
                o0 += __shfl_xor(o0, m, 64);
                o1 += __shfl_xor(o1, m, 64);
            }
            if (c == 0) {
                const int row = rt * 16 + g * 4 + reg;
                partials[w][row][0] = o0;
                partials[w][row][1] = o1;
            }
        }
    }
    __syncthreads();
    if (tid < 128) {
        const int row = tid >> 1, o = tid & 1;
        const float s = partials[0][row][o] + partials[1][row][o] +
                        partials[2][row][o] + partials[3][row][o];
        out[(blockRow + row) * 2 + o] = s;
    }
}

extern "C" void kernel_launch(void* const* d_in, const int* in_sizes, int n_in,
                              void* d_out, int out_size, void* d_ws, size_t ws_size,
                              hipStream_t stream) {
    const float* x   = (const float*)d_in[0];
    const float* fs  = (const float*)d_in[1];
    const float* thr = (const float*)d_in[2];
    const float* lw  = (const float*)d_in[3];
    float* out = (float*)d_out;

    const size_t FB_BYTES = (size_t)NT * ND * sizeof(__hip_bfloat16);  // 128 KB
    if (ws_size >= FB_BYTES) {
        __hip_bfloat16* Fb = (__hip_bfloat16*)d_ws;
        prep_kernel<<<256, 256, 0, stream>>>(fs, Fb);
        node_main<true><<<NB / ROWS, 256, 0, stream>>>(x, (const void*)Fb, thr, lw, out);
    } else {
        node_main<false><<<NB / ROWS, 256, 0, stream>>>(x, (const void*)fs, thr, lw, out);
    }
}

// Round 3
// 61.863 us; speedup vs baseline: 1.5688x; 1.0370x over previous
//
#include <hip/hip_runtime.h>
#include <hip/hip_bf16.h>

// Problem constants
#define NB   65536       // batch rows
#define ND   1024        // feature dim (K)
#define NT   64          // trees (N)
#define BK   128         // K-chunk in floats
#define NCH  (ND / BK)   // 8 chunks
#define ROWS 64          // rows per block

typedef __attribute__((ext_vector_type(8))) short bf16x8;
typedef __attribute__((ext_vector_type(4))) short bf16x4;
typedef __attribute__((ext_vector_type(4))) float f32x4;

__device__ __forceinline__ short f2bf_s(float f) {
    __hip_bfloat16 h = __float2bfloat16(f);
    return __builtin_bit_cast(short, h);
}

// ---- single kernel: 256 threads / 4 waves; block owns 64 rows; wave w owns trees [16w,16w+16) ----
__global__ __launch_bounds__(256, 4) void node_main(const float* __restrict__ x,
                                                    const float* __restrict__ F,
                                                    const float* __restrict__ thr,
                                                    const float* __restrict__ lw,
                                                    float* __restrict__ out) {
    __shared__ __align__(16) __hip_bfloat16 Abuf[2][ROWS * BK];   // 2 x 16 KB, XOR-swizzled bf16

    const int tid  = threadIdx.x;
    const int w    = tid >> 6;      // wave id -> n-tile (16 trees)
    const int lane = tid & 63;
    const int c    = lane & 15;     // MFMA col-within-16 (tree) / A-row-within-16
    const int g    = lane >> 4;     // k-group
    const long blockRow = (long)blockIdx.x * ROWS;

    // staging mapping: instruction i loads rows i*8 + (tid>>5); lanes 0..31 of each
    // row-half load a CONTIGUOUS 512B segment (full-line coalescing).
    const int srow = tid >> 5;      // 0..7
    const int scol = tid & 31;      // float4 index within the 512B row-chunk
    const float* xbase = x + blockRow * ND;

    // per-lane tree constants (tree fixed per lane)
    const int   t     = w * 16 + c;
    const float thr_t = thr[t];
    const float w00 = lw[t * 4 + 0], w01 = lw[t * 4 + 1];
    const float w10 = lw[t * 4 + 2], w11 = lw[t * 4 + 3];
    const float* Frow = F + (long)t * ND;   // L2-resident, cvt inline

    f32x4 acc[4];
#pragma unroll
    for (int rt = 0; rt < 4; ++rt) acc[rt] = (f32x4){0.f, 0.f, 0.f, 0.f};

    f32x4 rA[8];

    auto load_chunk = [&](int ch) {
#pragma unroll
        for (int i = 0; i < 8; ++i) {
            const f32x4* p = (const f32x4*)(xbase + (long)(i * 8 + srow) * ND + ch * BK + scol * 4);
            rA[i] = __builtin_nontemporal_load(p);   // streamed, no reuse: don't thrash L2
        }
    };
    auto stage_write = [&](int buf) {
#pragma unroll
        for (int i = 0; i < 8; ++i) {
            f32x4 a = rA[i];
            bf16x4 v;
            v[0] = f2bf_s(a[0]); v[1] = f2bf_s(a[1]);
            v[2] = f2bf_s(a[2]); v[3] = f2bf_s(a[3]);
            const int r = i * 8 + srow;
            const int s = (scol >> 1) ^ (r & 7);             // T2 XOR swizzle, 16B slots
            char* p = (char*)(&Abuf[buf][0]) + r * 256 + (s << 4) + ((scol & 1) << 3);
            *(bf16x4*)p = v;
        }
    };

    // prologue: fill buf0, issue chunk-1 loads
    load_chunk(0);
    stage_write(0);
    load_chunk(1);
    __syncthreads();

    for (int ch = 0; ch < NCH; ++ch) {
        const int cur = ch & 1;
        // ---- compute chunk ch ----
#pragma unroll
        for (int kk = 0; kk < 4; ++kk) {
            // B fragment: inline f32 -> bf16 (F is L2-resident; 256KB)
            const float* fp = Frow + ch * BK + kk * 32 + g * 8;
            f32x4 b0 = *(const f32x4*)(fp);
            f32x4 b1 = *(const f32x4*)(fp + 4);
            bf16x8 bfrag;
            bfrag[0] = f2bf_s(b0[0]); bfrag[1] = f2bf_s(b0[1]);
            bfrag[2] = f2bf_s(b0[2]); bfrag[3] = f2bf_s(b0[3]);
            bfrag[4] = f2bf_s(b1[0]); bfrag[5] = f2bf_s(b1[1]);
            bfrag[6] = f2bf_s(b1[2]); bfrag[7] = f2bf_s(b1[3]);
#pragma unroll
            for (int rt = 0; rt < 4; ++rt) {
                const int r    = rt * 16 + c;
                const int slot = (kk * 4 + g) ^ (r & 7);
                bf16x8 afrag = *(const bf16x8*)(&Abuf[cur][r * BK + slot * 8]);
                acc[rt] = __builtin_amdgcn_mfma_f32_16x16x32_bf16(afrag, bfrag, acc[rt], 0, 0, 0);
            }
        }
        // ---- stage chunk ch+1 (rA in flight from prev iter), issue chunk ch+2 ----
        if (ch < NCH - 1) {
            stage_write(cur ^ 1);
            if (ch < NCH - 2) load_chunk(ch + 2);
        }
        __syncthreads();
    }

    // ---- epilogue: sigmoid + leaf combine + tree reduction ----
    // partials aliased into Abuf (free after final barrier): [4 waves][64 rows][2 outs]
    float* partials = (float*)(&Abuf[0][0]);
#pragma unroll
    for (int rt = 0; rt < 4; ++rt) {
#pragma unroll
        for (int reg = 0; reg < 4; ++reg) {
            const float logit = acc[rt][reg] - thr_t;
            const float p = 1.0f / (1.0f + __expf(-logit));
            float o0 = w10 + p * (w00 - w10);
            float o1 = w11 + p * (w01 - w11);
            // butterfly over the 16 trees (c bits of lane)
#pragma unroll
            for (int m = 1; m < 16; m <<= 1) {
                o0 += __shfl_xor(o0, m, 64);
                o1 += __shfl_xor(o1, m, 64);
            }
            if (c == 0) {
                const int row = rt * 16 + g * 4 + reg;
                partials[(w * ROWS + row) * 2 + 0] = o0;
                partials[(w * ROWS + row) * 2 + 1] = o1;
            }
        }
    }
    __syncthreads();
    if (tid < 128) {
        const int row = tid >> 1, o = tid & 1;
        const float s = partials[(0 * ROWS + row) * 2 + o] + partials[(1 * ROWS + row) * 2 + o] +
                        partials[(2 * ROWS + row) * 2 + o] + partials[(3 * ROWS + row) * 2 + o];
        out[(blockRow + row) * 2 + o] = s;
    }
}

extern "C" void kernel_launch(void* const* d_in, const int* in_sizes, int n_in,
                              void* d_out, int out_size, void* d_ws, size_t ws_size,
                              hipStream_t stream) {
    const float* x   = (const float*)d_in[0];
    const float* fs  = (const float*)d_in[1];
    const float* thr = (const float*)d_in[2];
    const float* lw  = (const float*)d_in[3];
    float* out = (float*)d_out;
    (void)d_ws; (void)ws_size; (void)in_sizes; (void)n_in; (void)out_size;

    node_main<<<NB / ROWS, 256, 0, stream>>>(x, fs, thr, lw, out);
}